// Round 16
// baseline (230.701 us; speedup 1.0000x reference)
//
#include <hip/hip_runtime.h>

typedef _Float16 f16;
typedef f16 f16x8 __attribute__((ext_vector_type(8)));
typedef f16 f16x2 __attribute__((ext_vector_type(2)));
typedef __fp16 h16x2 __attribute__((ext_vector_type(2)));   // cvt_pkrtz return type
typedef float f32x4 __attribute__((ext_vector_type(4)));

#define PI_F 3.14159265358979323846f

constexpr int TP = 128;          // points per block (4 waves x 32 rows)
constexpr int FSTR = 136;        // LDS row stride in f16 (272 B, 16B-aligned)
constexpr int PLANE_ELEMS = 128 * 128 * 16;   // per-plane f32 elems in the INPUT
constexpr int IPLANE = 128 * 128 * 32;        // interleaved f16 elems per axis
constexpr int ILINE = 128 * 32;               // interleaved f16 elems per axis

// Feature layout (96): [0..47] color plane*line products (axis-major, 16 ch)
//   [48..71] enc d=0,1 | [72..83] enc d=2 | [84..86] ray | [87..95] zeros
// h-tile column packing: within each 32-col block, logical col c stored at
// p(c) = 2*(c&15) + (c>>4); W2h/W3p K-columns permuted identically in prep.

// ---------------------------------------------------------------------------
// Prep 1 (R14-verified): fold basis into W1 (tail layout), f16 weights
// (W2/W3 K-permuted), interleave lines.
// ---------------------------------------------------------------------------
__global__ void prep_small(const float* __restrict__ W1, const float* __restrict__ basisW,
                           const float* __restrict__ W2, const float* __restrict__ W3,
                           const float* __restrict__ dlines, const float* __restrict__ clines,
                           f16* __restrict__ W1p, f16* __restrict__ W2h, f16* __restrict__ W3p,
                           f16* __restrict__ linesI) {
    int t = blockIdx.x * 256 + threadIdx.x;
    if (t < 128 * 96) {
        int r = t / 96, c = t % 96;
        float v = 0.f;
        if (c < 48) {
            for (int m = 0; m < 27; m++) v += W1[r * 66 + m] * basisW[m * 48 + c];
        } else if (c < 84) {
            v = W1[r * 66 + 30 + (c - 48)];      // enc, linear d-major order
        } else if (c < 87) {
            v = W1[r * 66 + 27 + (c - 84)];      // ray
        }
        W1p[t] = (f16)v;
        return;
    }
    t -= 128 * 96;
    if (t < 128 * 128) {
        int n = t / 128, s = t % 128;
        int k = (s & ~31) + ((s & 31) >> 1) + 16 * (s & 1);   // inverse perm
        W2h[t] = (f16)W2[n * 128 + k];
        return;
    }
    t -= 128 * 128;
    if (t < 16 * 128) {
        int r = t / 128, s = t % 128;
        int k = (s & ~31) + ((s & 31) >> 1) + 16 * (s & 1);
        W3p[t] = (f16)(r < 3 ? W3[r * 128 + k] : 0.f);
        return;
    }
    t -= 16 * 128;
    if (t < 3 * ILINE) {
        int axis = t / ILINE;
        int rem = t % ILINE;
        int l = rem / 32, c = rem % 32;
        float v = (c < 16) ? dlines[axis * 2048 + c * 128 + l]
                           : clines[axis * 2048 + (c - 16) * 128 + l];
        linesI[t] = (f16)v;
    }
}

// ---------------------------------------------------------------------------
// Prep 2: planes -> planesI f16 [axis][y][x][c32] (c<16 density, c>=16 color)
// ---------------------------------------------------------------------------
__global__ void interleave_planes(const float* __restrict__ dplanes,
                                  const float* __restrict__ cplanes,
                                  f16* __restrict__ planesI) {
    __shared__ f16 s[128 * 34];
    int b = blockIdx.x;
    int axis = b >> 7;
    int y = b & 127;
    const float* dsrc = dplanes + (size_t)axis * PLANE_ELEMS + y * 128;
    const float* csrc = cplanes + (size_t)axis * PLANE_ELEMS + y * 128;
    int tid = threadIdx.x;
#pragma unroll
    for (int it = 0; it < 8; it++) {
        int c = it * 2 + (tid >> 7);
        int x = tid & 127;
        s[x * 34 + c]      = (f16)dsrc[(size_t)c * 16384 + x];
        s[x * 34 + 16 + c] = (f16)csrc[(size_t)c * 16384 + x];
    }
    __syncthreads();
    f16* dst = planesI + (size_t)(axis * 128 + y) * (128 * 32);
#pragma unroll
    for (int it = 0; it < 8; it++) {
        int d = it * 256 + tid;
        int x = d >> 4, cp = (d & 15) * 2;
        dst[2 * d]     = s[x * 34 + cp];
        dst[2 * d + 1] = s[x * 34 + cp + 1];
    }
}

// ---------------------------------------------------------------------------
// Main fused kernel — BARRIER-FREE wave-private decomposition.
// 256 threads / 128 points / 34 KB LDS -> 4 blocks/CU, 16 independent waves.
// Each wave owns rows [32w,32w+32): gather -> PE -> L1 -> L2 -> L3, all LDS
// traffic wave-private (ordering via lgkmcnt only, NO __syncthreads).
// B-fragments streamed from L2 per n-pair (4x duplication, overlappable).
// ---------------------------------------------------------------------------
__global__ __launch_bounds__(256, 4) void nerf_main(
    const float* __restrict__ pts, const float* __restrict__ rayu,
    const f16* __restrict__ planesI, const f16* __restrict__ linesI,
    const f16* __restrict__ W1p, const f16* __restrict__ W2h, const f16* __restrict__ W3p,
    const float* __restrict__ b1, const float* __restrict__ b2, const float* __restrict__ b3,
    float* __restrict__ out, int N) {
    __shared__ __align__(16) f16 tile[TP * FSTR];
    const int tid = threadIdx.x;
    const int p0 = blockIdx.x * TP;
    const int w = tid >> 6, lane = tid & 63, ar = lane & 15, kg = lane >> 4;
    const int rowb = 32 * w;                 // wave's private row band

    // ---------------- phase 1a: cooperative texture gather ----------------
    {
        const int grp = lane >> 2;           // 16 groups per wave
        const int q = lane & 3;
        const int qc = q - 2;
        const f16* pq = planesI + 8 * q;
        const f16* lq = linesI + 8 * q;
#pragma unroll
        for (int it = 0; it < 2; it++) {
            const int pi = rowb + 16 * it + grp;
            const int pp = p0 + pi;
            float g0 = pts[3 * pp + 0], g1 = pts[3 * pp + 1], g2 = pts[3 * pp + 2];
            float g[3] = {g0, g1, g2};
            float sigma = 0.f;
            f16* frow = &tile[pi * FSTR];
#pragma unroll
            for (int i = 0; i < 3; i++) {
                const int m0 = (i == 2) ? 1 : 0;
                const int m1 = (i == 0) ? 1 : 2;
                const int vm = 2 - i;
                float fx = (g[m0] + 1.f) * 63.5f;
                float fy = (g[m1] + 1.f) * 63.5f;
                float fl = (g[vm] + 1.f) * 63.5f;
                int ix0 = min((int)fx, 126);
                int iy0 = min((int)fy, 126);
                int il0 = min((int)fl, 126);
                float wx = fx - (float)ix0, wy = fy - (float)iy0, wl = fl - (float)il0;
                f16 w00 = (f16)((1.f - wx) * (1.f - wy));
                f16 w01 = (f16)(wx * (1.f - wy));
                f16 w10 = (f16)((1.f - wx) * wy);
                f16 w11 = (f16)(wx * wy);
                f16 wl1 = (f16)(1.f - wl), wlh = (f16)wl;
                const f16* c00 = pq + ((i * 128 + iy0) * 128 + ix0) * 32;
                const f16* c10 = c00 + 128 * 32;
                const f16* l0 = lq + (i * 128 + il0) * 32;
                f16x8 v00 = *(const f16x8*)c00;
                f16x8 v01 = *(const f16x8*)(c00 + 32);
                f16x8 v10 = *(const f16x8*)c10;
                f16x8 v11 = *(const f16x8*)(c10 + 32);
                f16x8 pb = v00 * w00 + v01 * w01 + v10 * w10 + v11 * w11;
                f16x8 lv = *(const f16x8*)l0 * wl1 + *(const f16x8*)(l0 + 32) * wlh;
                f16x8 prod = pb * lv;
                if (q < 2) {
                    const f16x2 one2 = {(f16)1.f, (f16)1.f};
#pragma unroll
                    for (int e = 0; e < 4; e++) {
                        f16x2 pr2 = {prod[2 * e], prod[2 * e + 1]};
                        sigma = __builtin_amdgcn_fdot2(pr2, one2, sigma, false);
                    }
                } else {
                    *(f16x8*)(frow + 16 * i + 8 * qc) = prod;
                }
            }
            sigma += __shfl_xor(sigma, 1);
            if (q == 0) out[3 * N + pp] = sigma;
        }
    }

    // ------- phase 1b: PE + ray (half-wave roles, wave-private rows) -------
    {
        const int role = lane >> 5;          // 0: enc d=0,1   1: enc d=2+ray+0s
        const int pi = rowb + (lane & 31);
        const int pp = p0 + pi;
        f16 tail[24];
        if (role == 0) {
            float r0 = rayu[3 * pp + 0], r1 = rayu[3 * pp + 1];
            float rv[2] = {r0, r1};
#pragma unroll
            for (int d = 0; d < 2; d++) {
                float f = rv[d] * PI_F;
                float s = __sinf(f), c = __cosf(f);
#pragma unroll
                for (int k = 0; k < 6; k++) {
                    tail[12 * d + k] = (f16)s;
                    tail[12 * d + 6 + k] = (f16)c;
                    float ns = 2.f * s * c;
                    float nc = 1.f - 2.f * s * s;
                    s = ns; c = nc;
                }
            }
        } else {
            float r0 = rayu[3 * pp + 0], r1 = rayu[3 * pp + 1], r2 = rayu[3 * pp + 2];
            float f = r2 * PI_F;
            float s = __sinf(f), c = __cosf(f);
#pragma unroll
            for (int k = 0; k < 6; k++) {
                tail[k] = (f16)s;
                tail[6 + k] = (f16)c;
                float ns = 2.f * s * c;
                float nc = 1.f - 2.f * s * s;
                s = ns; c = nc;
            }
            tail[12] = (f16)r0; tail[13] = (f16)r1; tail[14] = (f16)r2;
#pragma unroll
            for (int e = 15; e < 24; e++) tail[e] = (f16)0.f;
        }
#pragma unroll
        for (int j = 0; j < 3; j++)
            *(f16x8*)&tile[pi * FSTR + 48 + 24 * role + 8 * j] = *(const f16x8*)&tail[8 * j];
    }
    // NO __syncthreads() — all subsequent LDS traffic is wave-private.

    // ---------------- phase 2: MLP via MFMA, barrier-free ----------------
    // ---- L1: feat[32x96] @ W1p^T, n-pairs streamed ----
    {
        f16x8 a1[2][3];
#pragma unroll
        for (int mt = 0; mt < 2; mt++)
#pragma unroll
            for (int k = 0; k < 3; k++)
                a1[mt][k] = *(const f16x8*)&tile[(rowb + 16 * mt + ar) * FSTR + 32 * k + 8 * kg];
#pragma unroll
        for (int nb = 0; nb < 4; nb++) {
            f16x8 bf[2][3];
            float bias[2];
#pragma unroll
            for (int h = 0; h < 2; h++) {
                int n = 2 * nb + h;
#pragma unroll
                for (int k = 0; k < 3; k++)
                    bf[h][k] = *(const f16x8*)(W1p + (16 * n + ar) * 96 + 32 * k + 8 * kg);
                bias[h] = b1[16 * n + ar];
            }
            f32x4 acc[2][2];
#pragma unroll
            for (int mt = 0; mt < 2; mt++)
#pragma unroll
                for (int h = 0; h < 2; h++)
                    acc[mt][h] = (f32x4){bias[h], bias[h], bias[h], bias[h]};
            __builtin_amdgcn_s_setprio(1);
#pragma unroll
            for (int k = 0; k < 3; k++)
#pragma unroll
                for (int h = 0; h < 2; h++)
#pragma unroll
                    for (int mt = 0; mt < 2; mt++)
                        acc[mt][h] = __builtin_amdgcn_mfma_f32_16x16x32_f16(a1[mt][k], bf[h][k], acc[mt][h], 0, 0, 0);
            __builtin_amdgcn_s_setprio(0);
#pragma unroll
            for (int mt = 0; mt < 2; mt++)
#pragma unroll
                for (int j = 0; j < 4; j++) {
                    h16x2 pr = __builtin_amdgcn_cvt_pkrtz(fmaxf(acc[mt][0][j], 0.f),
                                                          fmaxf(acc[mt][1][j], 0.f));
                    *(h16x2*)&tile[(rowb + 16 * mt + 4 * kg + j) * FSTR + 32 * nb + 2 * ar] = pr;
                }
        }
    }

    // ---- L2: h1[32x128] @ W2h^T, n-pairs streamed ----
    {
        f16x8 a2[2][4];
#pragma unroll
        for (int mt = 0; mt < 2; mt++)
#pragma unroll
            for (int k = 0; k < 4; k++)
                a2[mt][k] = *(const f16x8*)&tile[(rowb + 16 * mt + ar) * FSTR + 32 * k + 8 * kg];
#pragma unroll
        for (int nb = 0; nb < 4; nb++) {
            f16x8 bf[2][4];
            float bias[2];
#pragma unroll
            for (int h = 0; h < 2; h++) {
                int n = 2 * nb + h;
#pragma unroll
                for (int k = 0; k < 4; k++)
                    bf[h][k] = *(const f16x8*)(W2h + (16 * n + ar) * 128 + 32 * k + 8 * kg);
                bias[h] = b2[16 * n + ar];
            }
            f32x4 acc[2][2];
#pragma unroll
            for (int mt = 0; mt < 2; mt++)
#pragma unroll
                for (int h = 0; h < 2; h++)
                    acc[mt][h] = (f32x4){bias[h], bias[h], bias[h], bias[h]};
            __builtin_amdgcn_s_setprio(1);
#pragma unroll
            for (int k = 0; k < 4; k++)
#pragma unroll
                for (int h = 0; h < 2; h++)
#pragma unroll
                    for (int mt = 0; mt < 2; mt++)
                        acc[mt][h] = __builtin_amdgcn_mfma_f32_16x16x32_f16(a2[mt][k], bf[h][k], acc[mt][h], 0, 0, 0);
            __builtin_amdgcn_s_setprio(0);
#pragma unroll
            for (int mt = 0; mt < 2; mt++)
#pragma unroll
                for (int j = 0; j < 4; j++) {
                    h16x2 pr = __builtin_amdgcn_cvt_pkrtz(fmaxf(acc[mt][0][j], 0.f),
                                                          fmaxf(acc[mt][1][j], 0.f));
                    *(h16x2*)&tile[(rowb + 16 * mt + 4 * kg + j) * FSTR + 32 * nb + 2 * ar] = pr;
                }
        }
    }

    // ---- L3: h2[32x128] @ W3p^T -> rgb ----
    {
        f16x8 a3[2][4];
#pragma unroll
        for (int mt = 0; mt < 2; mt++)
#pragma unroll
            for (int k = 0; k < 4; k++)
                a3[mt][k] = *(const f16x8*)&tile[(rowb + 16 * mt + ar) * FSTR + 32 * k + 8 * kg];
        f16x8 w3f[4];
#pragma unroll
        for (int k = 0; k < 4; k++)
            w3f[k] = *(const f16x8*)(W3p + ar * 128 + 32 * k + 8 * kg);
        const float bias3v = (ar < 3) ? b3[ar] : 0.f;
        f32x4 a3acc[2];
#pragma unroll
        for (int mt = 0; mt < 2; mt++) a3acc[mt] = (f32x4){bias3v, bias3v, bias3v, bias3v};
        __builtin_amdgcn_s_setprio(1);
#pragma unroll
        for (int k = 0; k < 4; k++)
#pragma unroll
            for (int mt = 0; mt < 2; mt++)
                a3acc[mt] = __builtin_amdgcn_mfma_f32_16x16x32_f16(a3[mt][k], w3f[k], a3acc[mt], 0, 0, 0);
        __builtin_amdgcn_s_setprio(0);
        if (ar < 3) {
#pragma unroll
            for (int mt = 0; mt < 2; mt++)
#pragma unroll
                for (int j = 0; j < 4; j++) {
                    int row = p0 + rowb + 16 * mt + 4 * kg + j;
                    out[3 * row + ar] = 1.f / (1.f + __expf(-a3acc[mt][j]));
                }
        }
    }
}

extern "C" void kernel_launch(void* const* d_in, const int* in_sizes, int n_in,
                              void* d_out, int out_size, void* d_ws, size_t ws_size,
                              hipStream_t stream) {
    const float* pts    = (const float*)d_in[0];
    const float* rayu   = (const float*)d_in[1];
    const float* dplanes = (const float*)d_in[2];
    const float* dlines  = (const float*)d_in[3];
    const float* cplanes = (const float*)d_in[4];
    const float* clines  = (const float*)d_in[5];
    const float* basisW  = (const float*)d_in[6];
    const float* W1 = (const float*)d_in[7];
    const float* b1 = (const float*)d_in[8];
    const float* W2 = (const float*)d_in[9];
    const float* b2 = (const float*)d_in[10];
    const float* W3 = (const float*)d_in[11];
    const float* b3 = (const float*)d_in[12];
    float* out = (float*)d_out;
    const int N = in_sizes[0] / 3;

    f16* planesI = (f16*)d_ws;                 // 3 * 128*128*32
    f16* linesI = planesI + 3 * IPLANE;        // 3 * 128*32
    f16* W1p = linesI + 3 * ILINE;             // 128*96
    f16* W2h = W1p + 128 * 96;                 // 128*128 (K-permuted)
    f16* W3p = W2h + 128 * 128;                // 16*128  (K-permuted)

    prep_small<<<168, 256, 0, stream>>>(W1, basisW, W2, W3, dlines, clines,
                                        W1p, W2h, W3p, linesI);
    interleave_planes<<<384, 256, 0, stream>>>(dplanes, cplanes, planesI);
    nerf_main<<<N / TP, 256, 0, stream>>>(pts, rayu, planesI, linesI,
                                          W1p, W2h, W3p, b1, b2, b3, out, N);
}

// Round 17
// 147.870 us; speedup vs baseline: 1.5602x; 1.5602x over previous
//
#include <hip/hip_runtime.h>

typedef _Float16 f16;
typedef f16 f16x8 __attribute__((ext_vector_type(8)));
typedef f16 f16x2 __attribute__((ext_vector_type(2)));
typedef float f32x4 __attribute__((ext_vector_type(4)));

#define PI_F 3.14159265358979323846f

constexpr int TP = 128;          // points per block
constexpr int FSTR = 136;        // LDS row stride in f16 (272 B, 16B-aligned)
constexpr int PLANE_ELEMS = 128 * 128 * 16;   // per-plane f32 elems in the INPUT
constexpr int IPLANE = 128 * 128 * 32;        // interleaved f16 elems per axis
constexpr int ILINE = 128 * 32;               // interleaved f16 elems per axis

// ---------------------------------------------------------------------------
// Prep 1 (R15-proven): fold basis into W1, f16 weights, interleave lines.
// Feature layout (96): [0..47] color plane*line products (axis-major, 16 ch)
//                      [48..50] ray, [51..86] enc, [87..95] 0
// NOTE: W2h/W3p are PLAIN row-major here (no K-perm needed — h writeback is
// scalar per-col in this structure, logical order preserved).
// ---------------------------------------------------------------------------
__global__ void prep_small(const float* __restrict__ W1, const float* __restrict__ basisW,
                           const float* __restrict__ W2, const float* __restrict__ W3,
                           const float* __restrict__ dlines, const float* __restrict__ clines,
                           f16* __restrict__ W1p, f16* __restrict__ W2h, f16* __restrict__ W3p,
                           f16* __restrict__ linesI) {
    int t = blockIdx.x * 256 + threadIdx.x;
    if (t < 128 * 96) {
        int r = t / 96, c = t % 96;
        float v = 0.f;
        if (c < 48) {
            for (int m = 0; m < 27; m++) v += W1[r * 66 + m] * basisW[m * 48 + c];
        } else if (c < 51) {
            v = W1[r * 66 + 27 + (c - 48)];
        } else if (c < 87) {
            v = W1[r * 66 + 30 + (c - 51)];
        }
        W1p[t] = (f16)v;
        return;
    }
    t -= 128 * 96;
    if (t < 128 * 128) { W2h[t] = (f16)W2[t]; return; }
    t -= 128 * 128;
    if (t < 16 * 128) {
        int r = t / 128, k = t % 128;
        W3p[t] = (f16)(r < 3 ? W3[r * 128 + k] : 0.f);
        return;
    }
    t -= 16 * 128;
    if (t < 3 * ILINE) {
        int axis = t / ILINE;
        int rem = t % ILINE;
        int l = rem / 32, c = rem % 32;
        float v = (c < 16) ? dlines[axis * 2048 + c * 128 + l]
                           : clines[axis * 2048 + (c - 16) * 128 + l];
        linesI[t] = (f16)v;
    }
}

// ---------------------------------------------------------------------------
// Prep 2: planes -> planesI f16 [axis][y][x][c32] (c<16 density, c>=16 color)
// ---------------------------------------------------------------------------
__global__ void interleave_planes(const float* __restrict__ dplanes,
                                  const float* __restrict__ cplanes,
                                  f16* __restrict__ planesI) {
    __shared__ f16 s[128 * 34];
    int b = blockIdx.x;
    int axis = b >> 7;
    int y = b & 127;
    const float* dsrc = dplanes + (size_t)axis * PLANE_ELEMS + y * 128;
    const float* csrc = cplanes + (size_t)axis * PLANE_ELEMS + y * 128;
    int tid = threadIdx.x;
#pragma unroll
    for (int it = 0; it < 8; it++) {
        int c = it * 2 + (tid >> 7);
        int x = tid & 127;
        s[x * 34 + c]      = (f16)dsrc[(size_t)c * 16384 + x];
        s[x * 34 + 16 + c] = (f16)csrc[(size_t)c * 16384 + x];
    }
    __syncthreads();
    f16* dst = planesI + (size_t)(axis * 128 + y) * (128 * 32);
#pragma unroll
    for (int it = 0; it < 8; it++) {
        int d = it * 256 + tid;
        int x = d >> 4, cp = (d & 15) * 2;
        dst[2 * d]     = s[x * 34 + cp];
        dst[2 * d + 1] = s[x * 34 + cp + 1];
    }
}

// ---------------------------------------------------------------------------
// Main fused kernel. 512 threads (8 waves) / 128 points / 68 KB LDS ->
// 2 blocks/CU = 16 waves/CU (same TLP as R15) with only THREE barriers:
//   gather+PE -> bar1 -> L1(read bufA) -> h1 -> bufB -> bar2
//   -> L2(read bufB) -> h2 -> bufA -> bar3 -> L3(read bufA) -> rgb.
// Double-buffering removes the WAR barriers of the in-place layout (5 -> 3).
// Each wave owns one 16-col n-tile (acc[8]); L3: wave w = m-tile w.
// ---------------------------------------------------------------------------
__global__ __launch_bounds__(512, 4) void nerf_main(
    const float* __restrict__ pts, const float* __restrict__ rayu,
    const f16* __restrict__ planesI, const f16* __restrict__ linesI,
    const f16* __restrict__ W1p, const f16* __restrict__ W2h, const f16* __restrict__ W3p,
    const float* __restrict__ b1, const float* __restrict__ b2, const float* __restrict__ b3,
    float* __restrict__ out, int N) {
    __shared__ __align__(16) f16 bufA[TP * FSTR];
    __shared__ __align__(16) f16 bufB[TP * FSTR];
    const int tid = threadIdx.x;
    const int p0 = blockIdx.x * TP;
    const int w = tid >> 6, lane = tid & 63, ar = lane & 15, kg = lane >> 4;
    const int col = 16 * w + ar;                 // this wave's output column

    // ---- prefetch L1 B-fragments + biases (completes during gather) ----
    f16x8 w1f[3];
#pragma unroll
    for (int k = 0; k < 3; k++)
        w1f[k] = *(const f16x8*)(W1p + col * 96 + 32 * k + 8 * kg);
    const float bias1v = b1[col];
    const float bias2v = b2[col];
    const float bias3v = (ar < 3) ? b3[ar] : 0.f;

    // ---------------- phase 1a: cooperative texture gather (1 pass) --------
    {
        const int grp = tid >> 2;                // 128 groups -> 128 points
        const int q = tid & 3;
        const int qc = q - 2;
        const f16* pq = planesI + 8 * q;
        const f16* lq = linesI + 8 * q;
        const int pi = grp;
        const int pp = p0 + pi;
        float g0 = pts[3 * pp + 0], g1 = pts[3 * pp + 1], g2 = pts[3 * pp + 2];
        float g[3] = {g0, g1, g2};
        float sigma = 0.f;
        f16* frow = &bufA[pi * FSTR];
#pragma unroll
        for (int i = 0; i < 3; i++) {
            const int m0 = (i == 2) ? 1 : 0;
            const int m1 = (i == 0) ? 1 : 2;
            const int vm = 2 - i;
            float fx = (g[m0] + 1.f) * 63.5f;
            float fy = (g[m1] + 1.f) * 63.5f;
            float fl = (g[vm] + 1.f) * 63.5f;
            int ix0 = min((int)fx, 126);
            int iy0 = min((int)fy, 126);
            int il0 = min((int)fl, 126);
            float wx = fx - (float)ix0, wy = fy - (float)iy0, wl = fl - (float)il0;
            f16 w00 = (f16)((1.f - wx) * (1.f - wy));
            f16 w01 = (f16)(wx * (1.f - wy));
            f16 w10 = (f16)((1.f - wx) * wy);
            f16 w11 = (f16)(wx * wy);
            f16 wl1 = (f16)(1.f - wl), wlh = (f16)wl;
            const f16* c00 = pq + ((i * 128 + iy0) * 128 + ix0) * 32;
            const f16* c10 = c00 + 128 * 32;
            const f16* l0 = lq + (i * 128 + il0) * 32;
            f16x8 v00 = *(const f16x8*)c00;
            f16x8 v01 = *(const f16x8*)(c00 + 32);
            f16x8 v10 = *(const f16x8*)c10;
            f16x8 v11 = *(const f16x8*)(c10 + 32);
            f16x8 pb = v00 * w00 + v01 * w01 + v10 * w10 + v11 * w11;
            f16x8 lv = *(const f16x8*)l0 * wl1 + *(const f16x8*)(l0 + 32) * wlh;
            f16x8 prod = pb * lv;
            if (q < 2) {
                const f16x2 one2 = {(f16)1.f, (f16)1.f};
#pragma unroll
                for (int e = 0; e < 4; e++) {
                    f16x2 pr2 = {prod[2 * e], prod[2 * e + 1]};
                    sigma = __builtin_amdgcn_fdot2(pr2, one2, sigma, false);
                }
            } else {
                *(f16x8*)(frow + 16 * i + 8 * qc) = prod;
            }
        }
        sigma += __shfl_xor(sigma, 1);
        if (q == 0) out[3 * N + pp] = sigma;
    }

    // ---------------- phase 1b: PE + ray, one thread per point -------------
    if (tid < TP) {
        const int pp = p0 + tid;
        float rx = rayu[3 * pp + 0], ry = rayu[3 * pp + 1], rz = rayu[3 * pp + 2];
        float rv[3] = {rx, ry, rz};
        f16 tail[48];
        tail[0] = (f16)rx; tail[1] = (f16)ry; tail[2] = (f16)rz;
#pragma unroll
        for (int d = 0; d < 3; d++) {
            float f = rv[d] * PI_F;
            float s = __sinf(f), c = __cosf(f);
#pragma unroll
            for (int k = 0; k < 6; k++) {
                tail[3 + 12 * d + k] = (f16)s;
                tail[3 + 12 * d + 6 + k] = (f16)c;
                float ns = 2.f * s * c;
                float nc = 1.f - 2.f * s * s;
                s = ns; c = nc;
            }
        }
#pragma unroll
        for (int e = 39; e < 48; e++) tail[e] = (f16)0.f;
#pragma unroll
        for (int j = 0; j < 6; j++)
            *(f16x8*)&bufA[tid * FSTR + 48 + 8 * j] = *(const f16x8*)&tail[8 * j];
    }
    __syncthreads();                                     // bar1: feat ready

    // ---------------- phase 2: MLP via MFMA ----------------
    f32x4 acc[8];

    // ---- L1: feat[128x96](bufA) @ W1p^T -> h1 col -> bufB ----
#pragma unroll
    for (int m = 0; m < 8; m++) acc[m] = (f32x4){bias1v, bias1v, bias1v, bias1v};
    __builtin_amdgcn_s_setprio(1);
#pragma unroll
    for (int mb = 0; mb < 2; mb++) {
#pragma unroll
        for (int k = 0; k < 3; k++) {
            f16x8 a[4];
#pragma unroll
            for (int mm = 0; mm < 4; mm++)
                a[mm] = *(const f16x8*)&bufA[(16 * (4 * mb + mm) + ar) * FSTR + 32 * k + 8 * kg];
#pragma unroll
            for (int mm = 0; mm < 4; mm++)
                acc[4 * mb + mm] = __builtin_amdgcn_mfma_f32_16x16x32_f16(a[mm], w1f[k], acc[4 * mb + mm], 0, 0, 0);
        }
    }
    __builtin_amdgcn_s_setprio(0);

    // prefetch L2 B-fragments (latency hidden under writeback)
    f16x8 w2f[4];
#pragma unroll
    for (int k = 0; k < 4; k++)
        w2f[k] = *(const f16x8*)(W2h + col * 128 + 32 * k + 8 * kg);

    // h1 writeback to bufB (no pre-barrier needed: different buffer)
#pragma unroll
    for (int m = 0; m < 8; m++)
#pragma unroll
        for (int j = 0; j < 4; j++)
            bufB[(16 * m + 4 * kg + j) * FSTR + col] = (f16)fmaxf(acc[m][j], 0.f);
    __syncthreads();                                     // bar2: h1 ready

    // ---- L2: h1[128x128](bufB) @ W2^T -> h2 col -> bufA ----
#pragma unroll
    for (int m = 0; m < 8; m++) acc[m] = (f32x4){bias2v, bias2v, bias2v, bias2v};
    __builtin_amdgcn_s_setprio(1);
#pragma unroll
    for (int mb = 0; mb < 2; mb++) {
#pragma unroll
        for (int k = 0; k < 4; k++) {
            f16x8 a[4];
#pragma unroll
            for (int mm = 0; mm < 4; mm++)
                a[mm] = *(const f16x8*)&bufB[(16 * (4 * mb + mm) + ar) * FSTR + 32 * k + 8 * kg];
#pragma unroll
            for (int mm = 0; mm < 4; mm++)
                acc[4 * mb + mm] = __builtin_amdgcn_mfma_f32_16x16x32_f16(a[mm], w2f[k], acc[4 * mb + mm], 0, 0, 0);
        }
    }
    __builtin_amdgcn_s_setprio(0);

    // prefetch L3 B-fragments
    f16x8 w3f[4];
#pragma unroll
    for (int k = 0; k < 4; k++)
        w3f[k] = *(const f16x8*)(W3p + ar * 128 + 32 * k + 8 * kg);

    // h2 writeback to bufA (feat dead; all L1 reads of bufA completed pre-bar2)
#pragma unroll
    for (int m = 0; m < 8; m++)
#pragma unroll
        for (int j = 0; j < 4; j++)
            bufA[(16 * m + 4 * kg + j) * FSTR + col] = (f16)fmaxf(acc[m][j], 0.f);
    __syncthreads();                                     // bar3: h2 ready

    // ---- L3: h2[128x128](bufA) @ W3p^T -> rgb; wave w owns m-tile w ----
    {
        f32x4 a3 = (f32x4){bias3v, bias3v, bias3v, bias3v};
        __builtin_amdgcn_s_setprio(1);
#pragma unroll
        for (int k = 0; k < 4; k++) {
            f16x8 a = *(const f16x8*)&bufA[(16 * w + ar) * FSTR + 32 * k + 8 * kg];
            a3 = __builtin_amdgcn_mfma_f32_16x16x32_f16(a, w3f[k], a3, 0, 0, 0);
        }
        __builtin_amdgcn_s_setprio(0);
        if (ar < 3) {
#pragma unroll
            for (int j = 0; j < 4; j++) {
                int row = p0 + 16 * w + 4 * kg + j;
                out[3 * row + ar] = 1.f / (1.f + __expf(-a3[j]));
            }
        }
    }
}

extern "C" void kernel_launch(void* const* d_in, const int* in_sizes, int n_in,
                              void* d_out, int out_size, void* d_ws, size_t ws_size,
                              hipStream_t stream) {
    const float* pts    = (const float*)d_in[0];
    const float* rayu   = (const float*)d_in[1];
    const float* dplanes = (const float*)d_in[2];
    const float* dlines  = (const float*)d_in[3];
    const float* cplanes = (const float*)d_in[4];
    const float* clines  = (const float*)d_in[5];
    const float* basisW  = (const float*)d_in[6];
    const float* W1 = (const float*)d_in[7];
    const float* b1 = (const float*)d_in[8];
    const float* W2 = (const float*)d_in[9];
    const float* b2 = (const float*)d_in[10];
    const float* W3 = (const float*)d_in[11];
    const float* b3 = (const float*)d_in[12];
    float* out = (float*)d_out;
    const int N = in_sizes[0] / 3;

    f16* planesI = (f16*)d_ws;                 // 3 * 128*128*32
    f16* linesI = planesI + 3 * IPLANE;        // 3 * 128*32
    f16* W1p = linesI + 3 * ILINE;             // 128*96
    f16* W2h = W1p + 128 * 96;                 // 128*128
    f16* W3p = W2h + 128 * 128;                // 16*128

    prep_small<<<168, 256, 0, stream>>>(W1, basisW, W2, W3, dlines, clines,
                                        W1p, W2h, W3p, linesI);
    interleave_planes<<<384, 256, 0, stream>>>(dplanes, cplanes, planesI);
    nerf_main<<<N / TP, 512, 0, stream>>>(pts, rayu, planesI, linesI,
                                          W1p, W2h, W3p, b1, b2, b3, out, N);
}

// Round 19
// 127.513 us; speedup vs baseline: 1.8092x; 1.1596x over previous
//
#include <hip/hip_runtime.h>

typedef _Float16 f16;
typedef f16 f16x8 __attribute__((ext_vector_type(8)));
typedef f16 f16x2 __attribute__((ext_vector_type(2)));
typedef __fp16 h16x2 __attribute__((ext_vector_type(2)));   // cvt_pkrtz return type
typedef float f32x4 __attribute__((ext_vector_type(4)));

#define PI_F 3.14159265358979323846f

constexpr int TP = 128;          // points per block (R10-proven geometry)
constexpr int FSTR = 136;        // LDS row stride in f16 (272 B, 16B-aligned)
constexpr int PLANE_ELEMS = 128 * 128 * 16;   // per-plane f32 elems in the INPUT
constexpr int IPLANE = 128 * 128 * 32;        // interleaved f16 elems per axis
constexpr int ILINE = 128 * 32;               // interleaved f16 elems per axis

// h-tile column packing: within each 32-col block, logical col c stored at
// p(c) = 2*(c&15) + (c>>4); W2h/W3p K-columns permuted identically in prep.

// ---------------------------------------------------------------------------
// Prep 1: fold basis into W1, f16 weights (W2/W3 K-permuted), interleave lines.
// Feature layout (96): [0..47] color plane*line products (axis-major, 16 ch)
//                      [48..50] ray, [51..86] enc, [87..95] 0
// ---------------------------------------------------------------------------
__global__ void prep_small(const float* __restrict__ W1, const float* __restrict__ basisW,
                           const float* __restrict__ W2, const float* __restrict__ W3,
                           const float* __restrict__ dlines, const float* __restrict__ clines,
                           f16* __restrict__ W1p, f16* __restrict__ W2h, f16* __restrict__ W3p,
                           f16* __restrict__ linesI) {
    int t = blockIdx.x * 256 + threadIdx.x;
    if (t < 128 * 96) {
        int r = t / 96, c = t % 96;
        float v = 0.f;
        if (c < 48) {
            for (int m = 0; m < 27; m++) v += W1[r * 66 + m] * basisW[m * 48 + c];
        } else if (c < 51) {
            v = W1[r * 66 + 27 + (c - 48)];
        } else if (c < 87) {
            v = W1[r * 66 + 30 + (c - 51)];
        }
        W1p[t] = (f16)v;
        return;
    }
    t -= 128 * 96;
    if (t < 128 * 128) {
        int n = t / 128, s = t % 128;
        int k = (s & ~31) + ((s & 31) >> 1) + 16 * (s & 1);   // inverse perm
        W2h[t] = (f16)W2[n * 128 + k];
        return;
    }
    t -= 128 * 128;
    if (t < 16 * 128) {
        int r = t / 128, s = t % 128;
        int k = (s & ~31) + ((s & 31) >> 1) + 16 * (s & 1);
        W3p[t] = (f16)(r < 3 ? W3[r * 128 + k] : 0.f);
        return;
    }
    t -= 16 * 128;
    if (t < 3 * ILINE) {
        int axis = t / ILINE;
        int rem = t % ILINE;
        int l = rem / 32, c = rem % 32;
        float v = (c < 16) ? dlines[axis * 2048 + c * 128 + l]
                           : clines[axis * 2048 + (c - 16) * 128 + l];
        linesI[t] = (f16)v;
    }
}

// ---------------------------------------------------------------------------
// Prep 2: planes -> planesI f16 [axis][y][x][c32] (c<16 density, c>=16 color)
// ---------------------------------------------------------------------------
__global__ void interleave_planes(const float* __restrict__ dplanes,
                                  const float* __restrict__ cplanes,
                                  f16* __restrict__ planesI) {
    __shared__ f16 s[128 * 34];
    int b = blockIdx.x;
    int axis = b >> 7;
    int y = b & 127;
    const float* dsrc = dplanes + (size_t)axis * PLANE_ELEMS + y * 128;
    const float* csrc = cplanes + (size_t)axis * PLANE_ELEMS + y * 128;
    int tid = threadIdx.x;
#pragma unroll
    for (int it = 0; it < 8; it++) {
        int c = it * 2 + (tid >> 7);
        int x = tid & 127;
        s[x * 34 + c]      = (f16)dsrc[(size_t)c * 16384 + x];
        s[x * 34 + 16 + c] = (f16)csrc[(size_t)c * 16384 + x];
    }
    __syncthreads();
    f16* dst = planesI + (size_t)(axis * 128 + y) * (128 * 32);
#pragma unroll
    for (int it = 0; it < 8; it++) {
        int d = it * 256 + tid;
        int x = d >> 4, cp = (d & 15) * 2;
        dst[2 * d]     = s[x * 34 + cp];
        dst[2 * d + 1] = s[x * 34 + cp + 1];
    }
}

// ---------------------------------------------------------------------------
// Main fused kernel (R15 = session best, restored).
// 256 threads / 128 points / 34 KB LDS -> 4 blocks/CU, ~13 active waves.
// Phase 1a: cooperative gather (4 lanes/point, 16B chunk each).
// Phase 1b: PE on tid<128.
// Phase 2: MFMA MLP, k-outer over 4-m blocks (8 indep chains), B prefetched,
//   packed h-writeback (cvt_pkrtz + b32, K-permuted weights), setprio(1)
//   around MFMA clusters.
// ---------------------------------------------------------------------------
__global__ __launch_bounds__(256, 4) void nerf_main(
    const float* __restrict__ pts, const float* __restrict__ rayu,
    const f16* __restrict__ planesI, const f16* __restrict__ linesI,
    const f16* __restrict__ W1p, const f16* __restrict__ W2h, const f16* __restrict__ W3p,
    const float* __restrict__ b1, const float* __restrict__ b2, const float* __restrict__ b3,
    float* __restrict__ out, int N) {
    __shared__ __align__(16) f16 tile[TP * FSTR];
    const int tid = threadIdx.x;
    const int p0 = blockIdx.x * TP;

    // lane mapping for phase 2 (needed for prefetch addressing)
    const int w = tid >> 6, l = tid & 63, ar = l & 15, kg = l >> 4;
    const int col0 = 32 * w + ar;
    const int col1 = 32 * w + 16 + ar;
    const int wbo = 32 * w + 2 * ar;

    // ---- prefetch L1 B-fragments + biases (completes during gather) ----
    f16x8 w1f0[3], w1f1[3];
#pragma unroll
    for (int k = 0; k < 3; k++) {
        w1f0[k] = *(const f16x8*)(W1p + col0 * 96 + 32 * k + 8 * kg);
        w1f1[k] = *(const f16x8*)(W1p + col1 * 96 + 32 * k + 8 * kg);
    }
    const float bias1_0 = b1[col0], bias1_1 = b1[col1];
    const float bias2_0 = b2[col0], bias2_1 = b2[col1];
    const float bias3v = (ar < 3) ? b3[ar] : 0.f;

    // ---------------- phase 1a: cooperative texture gather ----------------
    {
        const int grp = tid >> 2;
        const int q = tid & 3;
        const int qc = q - 2;
        const f16* pq = planesI + 8 * q;
        const f16* lq = linesI + 8 * q;
#pragma unroll
        for (int it = 0; it < 2; it++) {
            const int pi = it * 64 + grp;
            const int pp = p0 + pi;
            float g0 = pts[3 * pp + 0], g1 = pts[3 * pp + 1], g2 = pts[3 * pp + 2];
            float g[3] = {g0, g1, g2};
            float sigma = 0.f;
            f16* frow = &tile[pi * FSTR];
#pragma unroll
            for (int i = 0; i < 3; i++) {
                const int m0 = (i == 2) ? 1 : 0;
                const int m1 = (i == 0) ? 1 : 2;
                const int vm = 2 - i;
                float fx = (g[m0] + 1.f) * 63.5f;
                float fy = (g[m1] + 1.f) * 63.5f;
                float fl = (g[vm] + 1.f) * 63.5f;
                int ix0 = min((int)fx, 126);
                int iy0 = min((int)fy, 126);
                int il0 = min((int)fl, 126);
                float wx = fx - (float)ix0, wy = fy - (float)iy0, wl = fl - (float)il0;
                f16 w00 = (f16)((1.f - wx) * (1.f - wy));
                f16 w01 = (f16)(wx * (1.f - wy));
                f16 w10 = (f16)((1.f - wx) * wy);
                f16 w11 = (f16)(wx * wy);
                f16 wl1 = (f16)(1.f - wl), wlh = (f16)wl;
                const f16* c00 = pq + ((i * 128 + iy0) * 128 + ix0) * 32;
                const f16* c10 = c00 + 128 * 32;
                const f16* l0 = lq + (i * 128 + il0) * 32;
                f16x8 v00 = *(const f16x8*)c00;
                f16x8 v01 = *(const f16x8*)(c00 + 32);
                f16x8 v10 = *(const f16x8*)c10;
                f16x8 v11 = *(const f16x8*)(c10 + 32);
                f16x8 pb = v00 * w00 + v01 * w01 + v10 * w10 + v11 * w11;
                f16x8 lv = *(const f16x8*)l0 * wl1 + *(const f16x8*)(l0 + 32) * wlh;
                f16x8 prod = pb * lv;
                if (q < 2) {
                    const f16x2 one2 = {(f16)1.f, (f16)1.f};
#pragma unroll
                    for (int e = 0; e < 4; e++) {
                        f16x2 pr2 = {prod[2 * e], prod[2 * e + 1]};
                        sigma = __builtin_amdgcn_fdot2(pr2, one2, sigma, false);
                    }
                } else {
                    *(f16x8*)(frow + 16 * i + 8 * qc) = prod;
                }
            }
            sigma += __shfl_xor(sigma, 1);
            if (q == 0) out[3 * N + pp] = sigma;
        }
    }

    // ---------------- phase 1b: PE + ray, one thread per point ----------------
    if (tid < TP) {
        const int pp = p0 + tid;
        float rx = rayu[3 * pp + 0], ry = rayu[3 * pp + 1], rz = rayu[3 * pp + 2];
        float rv[3] = {rx, ry, rz};
        f16 tail[48];
        tail[0] = (f16)rx; tail[1] = (f16)ry; tail[2] = (f16)rz;
#pragma unroll
        for (int d = 0; d < 3; d++) {
            float f = rv[d] * PI_F;
            float s = __sinf(f), c = __cosf(f);
#pragma unroll
            for (int k = 0; k < 6; k++) {
                tail[3 + 12 * d + k] = (f16)s;
                tail[3 + 12 * d + 6 + k] = (f16)c;
                float ns = 2.f * s * c;
                float nc = 1.f - 2.f * s * s;
                s = ns; c = nc;
            }
        }
#pragma unroll
        for (int e = 39; e < 48; e++) tail[e] = (f16)0.f;
#pragma unroll
        for (int j = 0; j < 6; j++)
            *(f16x8*)&tile[tid * FSTR + 48 + 8 * j] = *(const f16x8*)&tail[8 * j];
    }
    __syncthreads();

    // ---------------- phase 2: MLP via MFMA ----------------
    f32x4 acc[8][2];

    // ---- L1: feat[128x96] @ W1p^T -> h1 (k-outer, 8 indep chains) ----
#pragma unroll
    for (int m = 0; m < 8; m++) {
        acc[m][0] = (f32x4){bias1_0, bias1_0, bias1_0, bias1_0};
        acc[m][1] = (f32x4){bias1_1, bias1_1, bias1_1, bias1_1};
    }
    __builtin_amdgcn_s_setprio(1);
#pragma unroll
    for (int mb = 0; mb < 2; mb++) {
#pragma unroll
        for (int k = 0; k < 3; k++) {
            f16x8 a[4];
#pragma unroll
            for (int mm = 0; mm < 4; mm++)
                a[mm] = *(const f16x8*)&tile[(16 * (4 * mb + mm) + ar) * FSTR + 32 * k + 8 * kg];
#pragma unroll
            for (int mm = 0; mm < 4; mm++) {
                int m = 4 * mb + mm;
                acc[m][0] = __builtin_amdgcn_mfma_f32_16x16x32_f16(a[mm], w1f0[k], acc[m][0], 0, 0, 0);
                acc[m][1] = __builtin_amdgcn_mfma_f32_16x16x32_f16(a[mm], w1f1[k], acc[m][1], 0, 0, 0);
            }
        }
    }
    __builtin_amdgcn_s_setprio(0);

    // prefetch L2 B-fragments (latency hidden under writeback barriers)
    f16x8 w2f0[4], w2f1[4];
#pragma unroll
    for (int k = 0; k < 4; k++) {
        w2f0[k] = *(const f16x8*)(W2h + col0 * 128 + 32 * k + 8 * kg);
        w2f1[k] = *(const f16x8*)(W2h + col1 * 128 + 32 * k + 8 * kg);
    }

    __syncthreads();
#pragma unroll
    for (int m = 0; m < 8; m++)
#pragma unroll
        for (int j = 0; j < 4; j++) {
            int row = 16 * m + 4 * kg + j;
            h16x2 pr = __builtin_amdgcn_cvt_pkrtz(fmaxf(acc[m][0][j], 0.f),
                                                  fmaxf(acc[m][1][j], 0.f));
            *(h16x2*)&tile[row * FSTR + wbo] = pr;
        }
    __syncthreads();

    // ---- L2: h1[128x128] @ W2^T -> h2 (k-outer) ----
#pragma unroll
    for (int m = 0; m < 8; m++) {
        acc[m][0] = (f32x4){bias2_0, bias2_0, bias2_0, bias2_0};
        acc[m][1] = (f32x4){bias2_1, bias2_1, bias2_1, bias2_1};
    }
    __builtin_amdgcn_s_setprio(1);
#pragma unroll
    for (int mb = 0; mb < 2; mb++) {
#pragma unroll
        for (int k = 0; k < 4; k++) {
            f16x8 a[4];
#pragma unroll
            for (int mm = 0; mm < 4; mm++)
                a[mm] = *(const f16x8*)&tile[(16 * (4 * mb + mm) + ar) * FSTR + 32 * k + 8 * kg];
#pragma unroll
            for (int mm = 0; mm < 4; mm++) {
                int m = 4 * mb + mm;
                acc[m][0] = __builtin_amdgcn_mfma_f32_16x16x32_f16(a[mm], w2f0[k], acc[m][0], 0, 0, 0);
                acc[m][1] = __builtin_amdgcn_mfma_f32_16x16x32_f16(a[mm], w2f1[k], acc[m][1], 0, 0, 0);
            }
        }
    }
    __builtin_amdgcn_s_setprio(0);

    // prefetch L3 B-fragments
    f16x8 w3f[4];
#pragma unroll
    for (int k = 0; k < 4; k++)
        w3f[k] = *(const f16x8*)(W3p + ar * 128 + 32 * k + 8 * kg);

    __syncthreads();
#pragma unroll
    for (int m = 0; m < 8; m++)
#pragma unroll
        for (int j = 0; j < 4; j++) {
            int row = 16 * m + 4 * kg + j;
            h16x2 pr = __builtin_amdgcn_cvt_pkrtz(fmaxf(acc[m][0][j], 0.f),
                                                  fmaxf(acc[m][1][j], 0.f));
            *(h16x2*)&tile[row * FSTR + wbo] = pr;
        }
    __syncthreads();

    // ---- L3: h2[128x128] @ W3p^T -> rgb (k-outer, 2 chains) ----
    {
        f32x4 a3[2];
#pragma unroll
        for (int mm = 0; mm < 2; mm++) a3[mm] = (f32x4){bias3v, bias3v, bias3v, bias3v};
        __builtin_amdgcn_s_setprio(1);
#pragma unroll
        for (int k = 0; k < 4; k++) {
#pragma unroll
            for (int mm = 0; mm < 2; mm++) {
                int m = 2 * w + mm;
                f16x8 a = *(const f16x8*)&tile[(16 * m + ar) * FSTR + 32 * k + 8 * kg];
                a3[mm] = __builtin_amdgcn_mfma_f32_16x16x32_f16(a, w3f[k], a3[mm], 0, 0, 0);
            }
        }
        __builtin_amdgcn_s_setprio(0);
        if (ar < 3) {
#pragma unroll
            for (int mm = 0; mm < 2; mm++) {
                int m = 2 * w + mm;
#pragma unroll
                for (int j = 0; j < 4; j++) {
                    int row = p0 + 16 * m + 4 * kg + j;
                    out[3 * row + ar] = 1.f / (1.f + __expf(-a3[mm][j]));
                }
            }
        }
    }
}

extern "C" void kernel_launch(void* const* d_in, const int* in_sizes, int n_in,
                              void* d_out, int out_size, void* d_ws, size_t ws_size,
                              hipStream_t stream) {
    const float* pts    = (const float*)d_in[0];
    const float* rayu   = (const float*)d_in[1];
    const float* dplanes = (const float*)d_in[2];
    const float* dlines  = (const float*)d_in[3];
    const float* cplanes = (const float*)d_in[4];
    const float* clines  = (const float*)d_in[5];
    const float* basisW  = (const float*)d_in[6];
    const float* W1 = (const float*)d_in[7];
    const float* b1 = (const float*)d_in[8];
    const float* W2 = (const float*)d_in[9];
    const float* b2 = (const float*)d_in[10];
    const float* W3 = (const float*)d_in[11];
    const float* b3 = (const float*)d_in[12];
    float* out = (float*)d_out;
    const int N = in_sizes[0] / 3;

    f16* planesI = (f16*)d_ws;                 // 3 * 128*128*32
    f16* linesI = planesI + 3 * IPLANE;        // 3 * 128*32
    f16* W1p = linesI + 3 * ILINE;             // 128*96
    f16* W2h = W1p + 128 * 96;                 // 128*128 (K-permuted)
    f16* W3p = W2h + 128 * 128;                // 16*128  (K-permuted)

    prep_small<<<168, 256, 0, stream>>>(W1, basisW, W2, W3, dlines, clines,
                                        W1p, W2h, W3p, linesI);
    interleave_planes<<<384, 256, 0, stream>>>(dplanes, cplanes, planesI);
    nerf_main<<<N / TP, 256, 0, stream>>>(pts, rayu, planesI, linesI,
                                          W1p, W2h, W3p, b1, b2, b3, out, N);
}

// Round 20
// 123.759 us; speedup vs baseline: 1.8641x; 1.0303x over previous
//
#include <hip/hip_runtime.h>

typedef _Float16 f16;
typedef f16 f16x8 __attribute__((ext_vector_type(8)));
typedef f16 f16x2 __attribute__((ext_vector_type(2)));
typedef __fp16 h16x2 __attribute__((ext_vector_type(2)));   // cvt_pkrtz return type
typedef float f32x4 __attribute__((ext_vector_type(4)));

#define PI_F 3.14159265358979323846f

constexpr int TP = 128;          // points per block (proven geometry)
constexpr int FSTR = 136;        // LDS row stride in f16 (272 B, 16B-aligned)
constexpr int PLANE_ELEMS = 128 * 128 * 16;   // per-plane f32 elems in the INPUT
constexpr int IPLANE = 128 * 128 * 32;        // interleaved f16 elems per axis
constexpr int ILINE = 128 * 32;               // interleaved f16 elems per axis

// h-tile column packing: within each 32-col block, logical col c stored at
// p(c) = 2*(c&15) + (c>>4); W2h/W3p K-columns permuted identically in prep.

// ---------------------------------------------------------------------------
// Merged prep kernel (saves one kernel launch + gap):
//   blocks [0,384): planes -> planesI f16 [axis][y][x][c32]
//   blocks [384,552): fold basis into W1, f16 weights (K-permuted), lines.
// ---------------------------------------------------------------------------
__global__ void prep_all(const float* __restrict__ dplanes, const float* __restrict__ cplanes,
                         const float* __restrict__ W1, const float* __restrict__ basisW,
                         const float* __restrict__ W2, const float* __restrict__ W3,
                         const float* __restrict__ dlines, const float* __restrict__ clines,
                         f16* __restrict__ planesI, f16* __restrict__ W1p,
                         f16* __restrict__ W2h, f16* __restrict__ W3p,
                         f16* __restrict__ linesI) {
    __shared__ f16 s[128 * 34];
    const int tid = threadIdx.x;
    if (blockIdx.x < 384) {
        // ---- interleave planes ----
        int b = blockIdx.x;
        int axis = b >> 7;
        int y = b & 127;
        const float* dsrc = dplanes + (size_t)axis * PLANE_ELEMS + y * 128;
        const float* csrc = cplanes + (size_t)axis * PLANE_ELEMS + y * 128;
#pragma unroll
        for (int it = 0; it < 8; it++) {
            int c = it * 2 + (tid >> 7);
            int x = tid & 127;
            s[x * 34 + c]      = (f16)dsrc[(size_t)c * 16384 + x];
            s[x * 34 + 16 + c] = (f16)csrc[(size_t)c * 16384 + x];
        }
        __syncthreads();
        f16* dst = planesI + (size_t)(axis * 128 + y) * (128 * 32);
#pragma unroll
        for (int it = 0; it < 8; it++) {
            int d = it * 256 + tid;
            int x = d >> 4, cp = (d & 15) * 2;
            dst[2 * d]     = s[x * 34 + cp];
            dst[2 * d + 1] = s[x * 34 + cp + 1];
        }
        return;
    }
    // ---- small-tensor prep (168 blocks x 256 = 43008 items, exact) ----
    int t = (blockIdx.x - 384) * 256 + tid;
    if (t < 128 * 96) {
        int r = t / 96, c = t % 96;
        float v = 0.f;
        if (c < 48) {
            for (int m = 0; m < 27; m++) v += W1[r * 66 + m] * basisW[m * 48 + c];
        } else if (c < 51) {
            v = W1[r * 66 + 27 + (c - 48)];
        } else if (c < 87) {
            v = W1[r * 66 + 30 + (c - 51)];
        }
        W1p[t] = (f16)v;
        return;
    }
    t -= 128 * 96;
    if (t < 128 * 128) {
        int n = t / 128, scol = t % 128;
        int k = (scol & ~31) + ((scol & 31) >> 1) + 16 * (scol & 1);   // inverse perm
        W2h[t] = (f16)W2[n * 128 + k];
        return;
    }
    t -= 128 * 128;
    if (t < 16 * 128) {
        int r = t / 128, scol = t % 128;
        int k = (scol & ~31) + ((scol & 31) >> 1) + 16 * (scol & 1);
        W3p[t] = (f16)(r < 3 ? W3[r * 128 + k] : 0.f);
        return;
    }
    t -= 16 * 128;
    if (t < 3 * ILINE) {
        int axis = t / ILINE;
        int rem = t % ILINE;
        int l = rem / 32, c = rem % 32;
        float v = (c < 16) ? dlines[axis * 2048 + c * 128 + l]
                           : clines[axis * 2048 + (c - 16) * 128 + l];
        linesI[t] = (f16)v;
    }
}

// ---------------------------------------------------------------------------
// Main fused kernel (R15 = session best, byte-identical structure).
// 256 threads / 128 points / 34 KB LDS -> 4 blocks/CU.
// Phase 1a: cooperative gather (4 lanes/point, 16B chunk each).
// Phase 1b: PE on tid<128.
// Phase 2: MFMA MLP, k-outer over 4-m blocks (8 indep chains), B prefetched,
//   packed h-writeback (cvt_pkrtz + b32, K-permuted weights), setprio(1)
//   around MFMA clusters.
// ---------------------------------------------------------------------------
__global__ __launch_bounds__(256, 4) void nerf_main(
    const float* __restrict__ pts, const float* __restrict__ rayu,
    const f16* __restrict__ planesI, const f16* __restrict__ linesI,
    const f16* __restrict__ W1p, const f16* __restrict__ W2h, const f16* __restrict__ W3p,
    const float* __restrict__ b1, const float* __restrict__ b2, const float* __restrict__ b3,
    float* __restrict__ out, int N) {
    __shared__ __align__(16) f16 tile[TP * FSTR];
    const int tid = threadIdx.x;
    const int p0 = blockIdx.x * TP;

    // lane mapping for phase 2 (needed for prefetch addressing)
    const int w = tid >> 6, l = tid & 63, ar = l & 15, kg = l >> 4;
    const int col0 = 32 * w + ar;
    const int col1 = 32 * w + 16 + ar;
    const int wbo = 32 * w + 2 * ar;

    // ---- prefetch L1 B-fragments + biases (completes during gather) ----
    f16x8 w1f0[3], w1f1[3];
#pragma unroll
    for (int k = 0; k < 3; k++) {
        w1f0[k] = *(const f16x8*)(W1p + col0 * 96 + 32 * k + 8 * kg);
        w1f1[k] = *(const f16x8*)(W1p + col1 * 96 + 32 * k + 8 * kg);
    }
    const float bias1_0 = b1[col0], bias1_1 = b1[col1];
    const float bias2_0 = b2[col0], bias2_1 = b2[col1];
    const float bias3v = (ar < 3) ? b3[ar] : 0.f;

    // ---------------- phase 1a: cooperative texture gather ----------------
    {
        const int grp = tid >> 2;
        const int q = tid & 3;
        const int qc = q - 2;
        const f16* pq = planesI + 8 * q;
        const f16* lq = linesI + 8 * q;
#pragma unroll
        for (int it = 0; it < 2; it++) {
            const int pi = it * 64 + grp;
            const int pp = p0 + pi;
            float g0 = pts[3 * pp + 0], g1 = pts[3 * pp + 1], g2 = pts[3 * pp + 2];
            float g[3] = {g0, g1, g2};
            float sigma = 0.f;
            f16* frow = &tile[pi * FSTR];
#pragma unroll
            for (int i = 0; i < 3; i++) {
                const int m0 = (i == 2) ? 1 : 0;
                const int m1 = (i == 0) ? 1 : 2;
                const int vm = 2 - i;
                float fx = (g[m0] + 1.f) * 63.5f;
                float fy = (g[m1] + 1.f) * 63.5f;
                float fl = (g[vm] + 1.f) * 63.5f;
                int ix0 = min((int)fx, 126);
                int iy0 = min((int)fy, 126);
                int il0 = min((int)fl, 126);
                float wx = fx - (float)ix0, wy = fy - (float)iy0, wl = fl - (float)il0;
                f16 w00 = (f16)((1.f - wx) * (1.f - wy));
                f16 w01 = (f16)(wx * (1.f - wy));
                f16 w10 = (f16)((1.f - wx) * wy);
                f16 w11 = (f16)(wx * wy);
                f16 wl1 = (f16)(1.f - wl), wlh = (f16)wl;
                const f16* c00 = pq + ((i * 128 + iy0) * 128 + ix0) * 32;
                const f16* c10 = c00 + 128 * 32;
                const f16* l0 = lq + (i * 128 + il0) * 32;
                f16x8 v00 = *(const f16x8*)c00;
                f16x8 v01 = *(const f16x8*)(c00 + 32);
                f16x8 v10 = *(const f16x8*)c10;
                f16x8 v11 = *(const f16x8*)(c10 + 32);
                f16x8 pb = v00 * w00 + v01 * w01 + v10 * w10 + v11 * w11;
                f16x8 lv = *(const f16x8*)l0 * wl1 + *(const f16x8*)(l0 + 32) * wlh;
                f16x8 prod = pb * lv;
                if (q < 2) {
                    const f16x2 one2 = {(f16)1.f, (f16)1.f};
#pragma unroll
                    for (int e = 0; e < 4; e++) {
                        f16x2 pr2 = {prod[2 * e], prod[2 * e + 1]};
                        sigma = __builtin_amdgcn_fdot2(pr2, one2, sigma, false);
                    }
                } else {
                    *(f16x8*)(frow + 16 * i + 8 * qc) = prod;
                }
            }
            sigma += __shfl_xor(sigma, 1);
            if (q == 0) out[3 * N + pp] = sigma;
        }
    }

    // ---------------- phase 1b: PE + ray, one thread per point ----------------
    if (tid < TP) {
        const int pp = p0 + tid;
        float rx = rayu[3 * pp + 0], ry = rayu[3 * pp + 1], rz = rayu[3 * pp + 2];
        float rv[3] = {rx, ry, rz};
        f16 tail[48];
        tail[0] = (f16)rx; tail[1] = (f16)ry; tail[2] = (f16)rz;
#pragma unroll
        for (int d = 0; d < 3; d++) {
            float f = rv[d] * PI_F;
            float s = __sinf(f), c = __cosf(f);
#pragma unroll
            for (int k = 0; k < 6; k++) {
                tail[3 + 12 * d + k] = (f16)s;
                tail[3 + 12 * d + 6 + k] = (f16)c;
                float ns = 2.f * s * c;
                float nc = 1.f - 2.f * s * s;
                s = ns; c = nc;
            }
        }
#pragma unroll
        for (int e = 39; e < 48; e++) tail[e] = (f16)0.f;
#pragma unroll
        for (int j = 0; j < 6; j++)
            *(f16x8*)&tile[tid * FSTR + 48 + 8 * j] = *(const f16x8*)&tail[8 * j];
    }
    __syncthreads();

    // ---------------- phase 2: MLP via MFMA ----------------
    f32x4 acc[8][2];

    // ---- L1: feat[128x96] @ W1p^T -> h1 (k-outer, 8 indep chains) ----
#pragma unroll
    for (int m = 0; m < 8; m++) {
        acc[m][0] = (f32x4){bias1_0, bias1_0, bias1_0, bias1_0};
        acc[m][1] = (f32x4){bias1_1, bias1_1, bias1_1, bias1_1};
    }
    __builtin_amdgcn_s_setprio(1);
#pragma unroll
    for (int mb = 0; mb < 2; mb++) {
#pragma unroll
        for (int k = 0; k < 3; k++) {
            f16x8 a[4];
#pragma unroll
            for (int mm = 0; mm < 4; mm++)
                a[mm] = *(const f16x8*)&tile[(16 * (4 * mb + mm) + ar) * FSTR + 32 * k + 8 * kg];
#pragma unroll
            for (int mm = 0; mm < 4; mm++) {
                int m = 4 * mb + mm;
                acc[m][0] = __builtin_amdgcn_mfma_f32_16x16x32_f16(a[mm], w1f0[k], acc[m][0], 0, 0, 0);
                acc[m][1] = __builtin_amdgcn_mfma_f32_16x16x32_f16(a[mm], w1f1[k], acc[m][1], 0, 0, 0);
            }
        }
    }
    __builtin_amdgcn_s_setprio(0);

    // prefetch L2 B-fragments (latency hidden under writeback barriers)
    f16x8 w2f0[4], w2f1[4];
#pragma unroll
    for (int k = 0; k < 4; k++) {
        w2f0[k] = *(const f16x8*)(W2h + col0 * 128 + 32 * k + 8 * kg);
        w2f1[k] = *(const f16x8*)(W2h + col1 * 128 + 32 * k + 8 * kg);
    }

    __syncthreads();
#pragma unroll
    for (int m = 0; m < 8; m++)
#pragma unroll
        for (int j = 0; j < 4; j++) {
            int row = 16 * m + 4 * kg + j;
            h16x2 pr = __builtin_amdgcn_cvt_pkrtz(fmaxf(acc[m][0][j], 0.f),
                                                  fmaxf(acc[m][1][j], 0.f));
            *(h16x2*)&tile[row * FSTR + wbo] = pr;
        }
    __syncthreads();

    // ---- L2: h1[128x128] @ W2^T -> h2 (k-outer) ----
#pragma unroll
    for (int m = 0; m < 8; m++) {
        acc[m][0] = (f32x4){bias2_0, bias2_0, bias2_0, bias2_0};
        acc[m][1] = (f32x4){bias2_1, bias2_1, bias2_1, bias2_1};
    }
    __builtin_amdgcn_s_setprio(1);
#pragma unroll
    for (int mb = 0; mb < 2; mb++) {
#pragma unroll
        for (int k = 0; k < 4; k++) {
            f16x8 a[4];
#pragma unroll
            for (int mm = 0; mm < 4; mm++)
                a[mm] = *(const f16x8*)&tile[(16 * (4 * mb + mm) + ar) * FSTR + 32 * k + 8 * kg];
#pragma unroll
            for (int mm = 0; mm < 4; mm++) {
                int m = 4 * mb + mm;
                acc[m][0] = __builtin_amdgcn_mfma_f32_16x16x32_f16(a[mm], w2f0[k], acc[m][0], 0, 0, 0);
                acc[m][1] = __builtin_amdgcn_mfma_f32_16x16x32_f16(a[mm], w2f1[k], acc[m][1], 0, 0, 0);
            }
        }
    }
    __builtin_amdgcn_s_setprio(0);

    // prefetch L3 B-fragments
    f16x8 w3f[4];
#pragma unroll
    for (int k = 0; k < 4; k++)
        w3f[k] = *(const f16x8*)(W3p + ar * 128 + 32 * k + 8 * kg);

    __syncthreads();
#pragma unroll
    for (int m = 0; m < 8; m++)
#pragma unroll
        for (int j = 0; j < 4; j++) {
            int row = 16 * m + 4 * kg + j;
            h16x2 pr = __builtin_amdgcn_cvt_pkrtz(fmaxf(acc[m][0][j], 0.f),
                                                  fmaxf(acc[m][1][j], 0.f));
            *(h16x2*)&tile[row * FSTR + wbo] = pr;
        }
    __syncthreads();

    // ---- L3: h2[128x128] @ W3p^T -> rgb (k-outer, 2 chains) ----
    {
        f32x4 a3[2];
#pragma unroll
        for (int mm = 0; mm < 2; mm++) a3[mm] = (f32x4){bias3v, bias3v, bias3v, bias3v};
        __builtin_amdgcn_s_setprio(1);
#pragma unroll
        for (int k = 0; k < 4; k++) {
#pragma unroll
            for (int mm = 0; mm < 2; mm++) {
                int m = 2 * w + mm;
                f16x8 a = *(const f16x8*)&tile[(16 * m + ar) * FSTR + 32 * k + 8 * kg];
                a3[mm] = __builtin_amdgcn_mfma_f32_16x16x32_f16(a, w3f[k], a3[mm], 0, 0, 0);
            }
        }
        __builtin_amdgcn_s_setprio(0);
        if (ar < 3) {
#pragma unroll
            for (int mm = 0; mm < 2; mm++) {
                int m = 2 * w + mm;
#pragma unroll
                for (int j = 0; j < 4; j++) {
                    int row = p0 + 16 * m + 4 * kg + j;
                    out[3 * row + ar] = 1.f / (1.f + __expf(-a3[mm][j]));
                }
            }
        }
    }
}

extern "C" void kernel_launch(void* const* d_in, const int* in_sizes, int n_in,
                              void* d_out, int out_size, void* d_ws, size_t ws_size,
                              hipStream_t stream) {
    const float* pts    = (const float*)d_in[0];
    const float* rayu   = (const float*)d_in[1];
    const float* dplanes = (const float*)d_in[2];
    const float* dlines  = (const float*)d_in[3];
    const float* cplanes = (const float*)d_in[4];
    const float* clines  = (const float*)d_in[5];
    const float* basisW  = (const float*)d_in[6];
    const float* W1 = (const float*)d_in[7];
    const float* b1 = (const float*)d_in[8];
    const float* W2 = (const float*)d_in[9];
    const float* b2 = (const float*)d_in[10];
    const float* W3 = (const float*)d_in[11];
    const float* b3 = (const float*)d_in[12];
    float* out = (float*)d_out;
    const int N = in_sizes[0] / 3;

    f16* planesI = (f16*)d_ws;                 // 3 * 128*128*32
    f16* linesI = planesI + 3 * IPLANE;        // 3 * 128*32
    f16* W1p = linesI + 3 * ILINE;             // 128*96
    f16* W2h = W1p + 128 * 96;                 // 128*128 (K-permuted)
    f16* W3p = W2h + 128 * 128;                // 16*128  (K-permuted)

    prep_all<<<552, 256, 0, stream>>>(dplanes, cplanes, W1, basisW, W2, W3,
                                      dlines, clines, planesI, W1p, W2h, W3p, linesI);
    nerf_main<<<N / TP, 256, 0, stream>>>(pts, rayu, planesI, linesI,
                                          W1p, W2h, W3p, b1, b2, b3, out, N);
}